// Round 4
// baseline (470.581 us; speedup 1.0000x reference)
//
#include <hip/hip_runtime.h>
#include <hip/hip_bf16.h>
#include <hip/hip_cooperative_groups.h>
#include <stdint.h>

namespace cg = cooperative_groups;

// Problem constants
#define BATCH 4096
#define NT    8192          // 2*BATCH
#define FD    256           // feature dim
#define TILE  128           // block tile of the pair matrix
#define BK    64            // K chunk per staging iteration
#define NBLK  64            // NT / TILE
#define NTRI  2080          // NBLK*(NBLK+1)/2 upper-triangle tiles
#define NUMK  5
#define GRID_MAX 1024

typedef __attribute__((ext_vector_type(8))) short bf16x8;  // 8 bf16 = 4 VGPRs
typedef __attribute__((ext_vector_type(4))) float f32x4;

// ---- workspace layout (bytes) ----
static const size_t WS_FB    = 0;                            // bf16 feats [8192][256] = 4 MiB
static const size_t WS_SQ    = (size_t)NT * FD * 2;          // sq[8192] f32
static const size_t WS_COLP  = WS_SQ + (size_t)NT * 4;       // colpart[1024][256] f32 = 1 MiB
static const size_t WS_COLP2 = WS_COLP + 1024 * 256 * 4;     // colpart2[32][256] f32
static const size_t WS_SQP   = WS_COLP2 + 32 * 256 * 4;      // sqpart[1024] f32
static const size_t WS_BLKP  = WS_SQP + 1024 * 4;            // blockpart[1024] f32
static const size_t WS_SCAL  = WS_BLKP + 1024 * 4;           // [0]=sumsq [1]=gamma

__device__ __forceinline__ unsigned short f2bf_rne(float x) {
    unsigned u = __float_as_uint(x);
    unsigned r = (u + 0x7fffu + ((u >> 16) & 1u)) >> 16;
    return (unsigned short)r;
}

__device__ __forceinline__ void async_copy16(void* lds, const void* g) {
    __builtin_amdgcn_global_load_lds(
        (__attribute__((address_space(1))) void*)(void*)(const_cast<void*>(g)),
        (__attribute__((address_space(3))) void*)lds, 16, 0, 0);
}

__global__ __launch_bounds__(256, 4) void mmd_all(
    const float* __restrict__ s_feat,
    const float* __restrict__ t_feat,
    unsigned short* __restrict__ fb,
    float* __restrict__ sq,
    float* __restrict__ colpart,
    float* __restrict__ colpart2,
    float* __restrict__ sqpart,
    float* __restrict__ blockpart,
    float* __restrict__ scal,
    float* __restrict__ out) {
    cg::grid_group grid = cg::this_grid();

    __shared__ __align__(16) unsigned short a_t[TILE * BK];   // 16 KiB (cp overlay in phase 1)
    __shared__ __align__(16) unsigned short b_t[TILE * BK];   // 16 KiB
    __shared__ float sqa[TILE], sqb[TILE];
    __shared__ float red[4];

    const int nb   = gridDim.x;
    const int bid  = blockIdx.x;
    const int tid  = threadIdx.x;
    const int w    = tid >> 6, lane = tid & 63;

    // ================= phase 1: convert + row norms + colsum partials =================
    {
        float* cpf = (float*)a_t;   // [4][256] per-wave column partials
        for (int rb = bid; rb < 1024; rb += nb) {   // rowblk = 8 rows
            float c0 = 0.f, c1 = 0.f, c2 = 0.f, c3 = 0.f, wtot = 0.f;
#pragma unroll
            for (int r = 0; r < 2; ++r) {
                int row = rb * 8 + w * 2 + r;
                const float* src = (row < BATCH) ? (s_feat + (size_t)row * FD)
                                                 : (t_feat + (size_t)(row - BATCH) * FD);
                float4 v = ((const float4*)src)[lane];
                unsigned int u01 = (unsigned)f2bf_rne(v.x) | ((unsigned)f2bf_rne(v.y) << 16);
                unsigned int u23 = (unsigned)f2bf_rne(v.z) | ((unsigned)f2bf_rne(v.w) << 16);
                ((uint2*)(fb + (size_t)row * FD))[lane] = make_uint2(u01, u23);
                float ss = v.x * v.x + v.y * v.y + v.z * v.z + v.w * v.w;
                for (int off = 32; off; off >>= 1) ss += __shfl_down(ss, off);
                if (lane == 0) { sq[row] = ss; wtot += ss; }
                c0 += v.x; c1 += v.y; c2 += v.z; c3 += v.w;
            }
            cpf[w * 256 + 4 * lane + 0] = c0;
            cpf[w * 256 + 4 * lane + 1] = c1;
            cpf[w * 256 + 4 * lane + 2] = c2;
            cpf[w * 256 + 4 * lane + 3] = c3;
            if (lane == 0) red[w] = wtot;
            __syncthreads();
            colpart[rb * 256 + tid] =
                cpf[tid] + cpf[256 + tid] + cpf[512 + tid] + cpf[768 + tid];
            if (tid == 0) sqpart[rb] = red[0] + red[1] + red[2] + red[3];
            __syncthreads();
        }
    }
    __threadfence();
    grid.sync();

    // ================= phase 2a: first-stage reduction =================
    for (int j = bid; j < 32; j += nb) {
        float acc = 0.f;
#pragma unroll 8
        for (int i = 0; i < 32; ++i) acc += colpart[(j * 32 + i) * 256 + tid];
        colpart2[j * 256 + tid] = acc;
    }
    if (bid == 32) {
        float sp = 0.f;
#pragma unroll
        for (int k2 = 0; k2 < 4; ++k2) sp += sqpart[tid + 256 * k2];
        for (int off = 32; off; off >>= 1) sp += __shfl_down(sp, off);
        if (lane == 0) red[w] = sp;
        __syncthreads();
        if (tid == 0) scal[0] = red[0] + red[1] + red[2] + red[3];   // sum of ||f||^2
    }
    __threadfence();
    grid.sync();

    // ================= phase 2b: gamma =================
    if (bid == 0) {
        float cs = 0.f;
#pragma unroll 8
        for (int b2 = 0; b2 < 32; ++b2) cs += colpart2[b2 * 256 + tid];
        float vv = cs * cs;
        for (int off = 32; off; off >>= 1) vv += __shfl_down(vv, off);
        if (lane == 0) red[w] = vv;
        __syncthreads();
        if (tid == 0) {
            float s2    = red[0] + red[1] + red[2] + red[3];   // ||colsum||^2
            float sumsq = scal[0];
            // sum(distances) = 2*n*sum(sq) - 2*||colsum||^2  (diag clamp negligible)
            float sumd = 2.0f * (float)NT * sumsq - 2.0f * s2;
            float n2n  = (float)((long long)NT * NT - NT);
            scal[1]    = 0.25f * (n2n / sumd);   // bandwidth / 2^(NUM_KERNELS//2)
        }
    }
    __threadfence();
    grid.sync();

    // ================= phase 3: persistent GEMM + gaussian mixture =================
    const float ng0 = -scal[1];
    const int wm   = w & 1, wn = w >> 1;          // 2x2 waves over 128x128
    const int quad = lane >> 4, m16 = lane & 15;
    const int lrow   = lane >> 3;                 // 0..7 row within 8-row group
    const int gc     = (lane & 7) ^ lrow;         // XOR-swizzle: slot p holds chunk p^(row&7)
    float blocksum = 0.f;

    for (int tt = bid; tt < NTRI; tt += nb) {
        // decode upper-triangle linear index -> (bi, bj)
        int u = tt, bi = 0;
        while (u >= NBLK - bi) { u -= NBLK - bi; ++bi; }
        const int bj = bi + u;
        const size_t rowA0 = (size_t)bi * TILE;
        const size_t rowB0 = (size_t)bj * TILE;

        if (tid < TILE) sqa[tid] = sq[rowA0 + tid];
        else            sqb[tid - TILE] = sq[rowB0 + (tid - TILE)];

        const f32x4 fzero = {0.f, 0.f, 0.f, 0.f};
        f32x4 acc[4][4];
#pragma unroll
        for (int a = 0; a < 4; ++a)
#pragma unroll
            for (int b = 0; b < 4; ++b) acc[a][b] = fzero;

        for (int k0 = 0; k0 < FD; k0 += BK) {
            __syncthreads();   // protect LDS from previous reads (and sqa/sqb write)
#pragma unroll
            for (int q = 0; q < 4; ++q) {
                int r = q * 32 + w * 8 + lrow;
                async_copy16(&a_t[(q * 32 + w * 8) * BK],
                             fb + (rowA0 + r) * FD + k0 + gc * 8);
            }
#pragma unroll
            for (int q = 0; q < 4; ++q) {
                int r = q * 32 + w * 8 + lrow;
                async_copy16(&b_t[(q * 32 + w * 8) * BK],
                             fb + (rowB0 + r) * FD + k0 + gc * 8);
            }
            __syncthreads();   // drains vmcnt per barrier semantics

#pragma unroll
            for (int kk = 0; kk < BK; kk += 32) {
                bf16x8 af[4], bf[4];
                const int cl = (kk >> 3) + quad;   // logical 16B chunk
#pragma unroll
                for (int tm = 0; tm < 4; ++tm) {
                    int row = wm * 64 + tm * 16 + m16;
                    int p = cl ^ (row & 7);
                    af[tm] = *(const bf16x8*)&a_t[row * BK + p * 8];
                }
#pragma unroll
                for (int tn = 0; tn < 4; ++tn) {
                    int row = wn * 64 + tn * 16 + m16;
                    int p = cl ^ (row & 7);
                    bf[tn] = *(const bf16x8*)&b_t[row * BK + p * 8];
                }
#pragma unroll
                for (int tm = 0; tm < 4; ++tm)
#pragma unroll
                    for (int tn = 0; tn < 4; ++tn)
                        acc[tm][tn] = __builtin_amdgcn_mfma_f32_16x16x32_bf16(
                            af[tm], bf[tn], acc[tm][tn], 0, 0, 0);
            }
        }

        // ---- epilogue: d = sq_i + sq_j - 2 dot, clamp, e + e^2 + e^4 + e^8 + e^16 ----
        float lsum = 0.f;
#pragma unroll
        for (int tm = 0; tm < 4; ++tm) {
            const int i0 = wm * 64 + tm * 16 + quad * 4;
            float sqi[4] = {sqa[i0 + 0], sqa[i0 + 1], sqa[i0 + 2], sqa[i0 + 3]};
#pragma unroll
            for (int tn = 0; tn < 4; ++tn) {
                const int j = wn * 64 + tn * 16 + m16;
                const float sqj = sqb[j];
#pragma unroll
                for (int r = 0; r < 4; ++r) {
                    float d = fmaf(-2.f, acc[tm][tn][r], sqi[r] + sqj);
                    d = fmaxf(d, 0.f);
                    float e1 = __expf(d * ng0);
                    float e2 = e1 * e1, e4 = e2 * e2, e8 = e4 * e4, e16 = e8 * e8;
                    lsum += (e1 + e2) + (e4 + e8) + e16;
                }
            }
        }
        for (int off = 32; off; off >>= 1) lsum += __shfl_down(lsum, off);
        if (lane == 0) red[w] = lsum;
        __syncthreads();
        float wgt;
        if (bi == bj) wgt = 1.f;
        else wgt = ((bi < NBLK / 2) == (bj < NBLK / 2)) ? 2.f : -2.f;
        blocksum += (red[0] + red[1] + red[2] + red[3]) *
                    (wgt * (1.f / NUMK) * (1.f / 16777216.f));   // / (5 * 4096^2)
    }
    if (tid == 0) blockpart[bid] = blocksum;
    __threadfence();
    grid.sync();

    // ================= phase 4: final reduction =================
    if (bid == 0) {
        float s = 0.f;
        for (int i = tid; i < nb; i += 256) s += blockpart[i];
        for (int off = 32; off; off >>= 1) s += __shfl_down(s, off);
        if (lane == 0) red[w] = s;
        __syncthreads();
        if (tid == 0) out[0] = red[0] + red[1] + red[2] + red[3];
    }
}

extern "C" void kernel_launch(void* const* d_in, const int* in_sizes, int n_in,
                              void* d_out, int out_size, void* d_ws, size_t ws_size,
                              hipStream_t stream) {
    const float* s_feat = (const float*)d_in[0];
    const float* t_feat = (const float*)d_in[1];
    char* ws = (char*)d_ws;
    unsigned short* fb = (unsigned short*)(ws + WS_FB);
    float* sq        = (float*)(ws + WS_SQ);
    float* colpart   = (float*)(ws + WS_COLP);
    float* colpart2  = (float*)(ws + WS_COLP2);
    float* sqpart    = (float*)(ws + WS_SQP);
    float* blockpart = (float*)(ws + WS_BLKP);
    float* scal      = (float*)(ws + WS_SCAL);
    float* out       = (float*)d_out;

    int occ = 0;
    hipOccupancyMaxActiveBlocksPerMultiprocessor(&occ, mmd_all, 256, 0);
    if (occ < 1) occ = 1;
    long long nbl = (long long)occ * 256;
    if (nbl > GRID_MAX) nbl = GRID_MAX;

    void* args[] = {(void*)&s_feat, (void*)&t_feat, (void*)&fb, (void*)&sq,
                    (void*)&colpart, (void*)&colpart2, (void*)&sqpart,
                    (void*)&blockpart, (void*)&scal, (void*)&out};
    hipLaunchCooperativeKernel((void*)mmd_all, dim3((unsigned)nbl), dim3(256),
                               args, 0, stream);
}

// Round 5
// 299.920 us; speedup vs baseline: 1.5690x; 1.5690x over previous
//
#include <hip/hip_runtime.h>
#include <hip/hip_bf16.h>
#include <hip/hip_cooperative_groups.h>
#include <stdint.h>

namespace cg = cooperative_groups;

// Problem constants
#define BATCH 4096
#define NT    8192          // 2*BATCH
#define FD    256           // feature dim
#define TILE  128           // block tile of the pair matrix
#define BK    64            // K chunk per staging iteration
#define NBLK  64            // NT / TILE
#define NTRI  2080          // NBLK*(NBLK+1)/2 upper-triangle tiles
#define NUMK  5
#define GRID_MAX 1024

typedef __attribute__((ext_vector_type(8))) short bf16x8;  // 8 bf16 = 4 VGPRs
typedef __attribute__((ext_vector_type(4))) float f32x4;

// ---- workspace layout (bytes) ----
static const size_t WS_FB    = 0;                            // bf16 feats [8192][256] = 4 MiB
static const size_t WS_SQ    = (size_t)NT * FD * 2;          // sq[8192] f32
static const size_t WS_COLP  = WS_SQ + (size_t)NT * 4;       // colpart[1024][256] f32 = 1 MiB
static const size_t WS_COLP2 = WS_COLP + 1024 * 256 * 4;     // colpart2[32][256] f32
static const size_t WS_SQP   = WS_COLP2 + 32 * 256 * 4;      // sqpart[1024] f32
static const size_t WS_BLKP  = WS_SQP + 1024 * 4;            // blockpart[1024] f32
static const size_t WS_SCAL  = WS_BLKP + 1024 * 4;           // [0]=sumsq [1]=gamma

__device__ __forceinline__ unsigned short f2bf_rne(float x) {
    unsigned u = __float_as_uint(x);
    unsigned r = (u + 0x7fffu + ((u >> 16) & 1u)) >> 16;
    return (unsigned short)r;
}

__device__ __forceinline__ void async_copy16(void* lds, const void* g) {
    __builtin_amdgcn_global_load_lds(
        (__attribute__((address_space(1))) void*)(void*)(const_cast<void*>(g)),
        (__attribute__((address_space(3))) void*)lds, 16, 0, 0);
}

// NOTE: no min-waves arg! With 64 AGPRs of accumulator, __launch_bounds__(256,4)
// caps arch VGPRs at 64 (unified file: 512/4 - 64) and spills catastrophically
// (R3/R4: WRITE_SIZE 8-57 MB of scratch traffic). Plain (256) gives ~96 arch
// VGPRs + 64 AGPR = 160/wave -> 3 waves/SIMD, no spill.
__global__ __launch_bounds__(256) void mmd_all(
    const float* __restrict__ s_feat,
    const float* __restrict__ t_feat,
    unsigned short* __restrict__ fb,
    float* __restrict__ sq,
    float* __restrict__ colpart,
    float* __restrict__ colpart2,
    float* __restrict__ sqpart,
    float* __restrict__ blockpart,
    float* __restrict__ scal,
    float* __restrict__ out) {
    cg::grid_group grid = cg::this_grid();

    __shared__ __align__(16) unsigned short a_t[TILE * BK];   // 16 KiB (cp overlay in phase 1)
    __shared__ __align__(16) unsigned short b_t[TILE * BK];   // 16 KiB
    __shared__ float sqa[TILE], sqb[TILE];
    __shared__ float red[4];

    const int nb   = gridDim.x;
    const int bid  = blockIdx.x;
    const int tid  = threadIdx.x;
    const int w    = tid >> 6, lane = tid & 63;

    // ================= phase 1: convert + row norms + colsum partials =================
    {
        float* cpf = (float*)a_t;   // [4][256] per-wave column partials
        for (int rb = bid; rb < 1024; rb += nb) {   // rowblk = 8 rows
            float c0 = 0.f, c1 = 0.f, c2 = 0.f, c3 = 0.f, wtot = 0.f;
#pragma unroll
            for (int r = 0; r < 2; ++r) {
                int row = rb * 8 + w * 2 + r;
                const float* src = (row < BATCH) ? (s_feat + (size_t)row * FD)
                                                 : (t_feat + (size_t)(row - BATCH) * FD);
                float4 v = ((const float4*)src)[lane];
                unsigned int u01 = (unsigned)f2bf_rne(v.x) | ((unsigned)f2bf_rne(v.y) << 16);
                unsigned int u23 = (unsigned)f2bf_rne(v.z) | ((unsigned)f2bf_rne(v.w) << 16);
                ((uint2*)(fb + (size_t)row * FD))[lane] = make_uint2(u01, u23);
                float ss = v.x * v.x + v.y * v.y + v.z * v.z + v.w * v.w;
                for (int off = 32; off; off >>= 1) ss += __shfl_down(ss, off);
                if (lane == 0) { sq[row] = ss; wtot += ss; }
                c0 += v.x; c1 += v.y; c2 += v.z; c3 += v.w;
            }
            cpf[w * 256 + 4 * lane + 0] = c0;
            cpf[w * 256 + 4 * lane + 1] = c1;
            cpf[w * 256 + 4 * lane + 2] = c2;
            cpf[w * 256 + 4 * lane + 3] = c3;
            if (lane == 0) red[w] = wtot;
            __syncthreads();
            colpart[rb * 256 + tid] =
                cpf[tid] + cpf[256 + tid] + cpf[512 + tid] + cpf[768 + tid];
            if (tid == 0) sqpart[rb] = red[0] + red[1] + red[2] + red[3];
            __syncthreads();
        }
    }
    __threadfence();
    grid.sync();

    // ================= phase 2a: first-stage reduction =================
    for (int j = bid; j < 32; j += nb) {
        float acc = 0.f;
#pragma unroll 8
        for (int i = 0; i < 32; ++i) acc += colpart[(j * 32 + i) * 256 + tid];
        colpart2[j * 256 + tid] = acc;
    }
    if (bid == 32) {
        float sp = 0.f;
#pragma unroll
        for (int k2 = 0; k2 < 4; ++k2) sp += sqpart[tid + 256 * k2];
        for (int off = 32; off; off >>= 1) sp += __shfl_down(sp, off);
        if (lane == 0) red[w] = sp;
        __syncthreads();
        if (tid == 0) scal[0] = red[0] + red[1] + red[2] + red[3];   // sum of ||f||^2
    }
    __threadfence();
    grid.sync();

    // ================= phase 2b: gamma =================
    if (bid == 0) {
        float cs = 0.f;
#pragma unroll 8
        for (int b2 = 0; b2 < 32; ++b2) cs += colpart2[b2 * 256 + tid];
        float vv = cs * cs;
        for (int off = 32; off; off >>= 1) vv += __shfl_down(vv, off);
        if (lane == 0) red[w] = vv;
        __syncthreads();
        if (tid == 0) {
            float s2    = red[0] + red[1] + red[2] + red[3];   // ||colsum||^2
            float sumsq = scal[0];
            // sum(distances) = 2*n*sum(sq) - 2*||colsum||^2  (diag clamp negligible)
            float sumd = 2.0f * (float)NT * sumsq - 2.0f * s2;
            float n2n  = (float)((long long)NT * NT - NT);
            scal[1]    = 0.25f * (n2n / sumd);   // bandwidth / 2^(NUM_KERNELS//2)
        }
    }
    __threadfence();
    grid.sync();

    // ================= phase 3: persistent GEMM + gaussian mixture =================
    const float ng0 = -scal[1];
    const int wm   = w & 1, wn = w >> 1;          // 2x2 waves over 128x128
    const int quad = lane >> 4, m16 = lane & 15;
    const int lrow   = lane >> 3;                 // 0..7 row within 8-row group
    const int gc     = (lane & 7) ^ lrow;         // XOR-swizzle: slot p holds chunk p^(row&7)
    float blocksum = 0.f;

    for (int tt = bid; tt < NTRI; tt += nb) {
        // decode upper-triangle linear index -> (bi, bj)
        int u = tt, bi = 0;
        while (u >= NBLK - bi) { u -= NBLK - bi; ++bi; }
        const int bj = bi + u;
        const size_t rowA0 = (size_t)bi * TILE;
        const size_t rowB0 = (size_t)bj * TILE;

        if (tid < TILE) sqa[tid] = sq[rowA0 + tid];
        else            sqb[tid - TILE] = sq[rowB0 + (tid - TILE)];

        const f32x4 fzero = {0.f, 0.f, 0.f, 0.f};
        f32x4 acc[4][4];
#pragma unroll
        for (int a = 0; a < 4; ++a)
#pragma unroll
            for (int b = 0; b < 4; ++b) acc[a][b] = fzero;

        for (int k0 = 0; k0 < FD; k0 += BK) {
            __syncthreads();   // protect LDS from previous reads (and sqa/sqb write)
#pragma unroll
            for (int q = 0; q < 4; ++q) {
                int r = q * 32 + w * 8 + lrow;
                async_copy16(&a_t[(q * 32 + w * 8) * BK],
                             fb + (rowA0 + r) * FD + k0 + gc * 8);
            }
#pragma unroll
            for (int q = 0; q < 4; ++q) {
                int r = q * 32 + w * 8 + lrow;
                async_copy16(&b_t[(q * 32 + w * 8) * BK],
                             fb + (rowB0 + r) * FD + k0 + gc * 8);
            }
            __syncthreads();   // drains vmcnt per barrier semantics

#pragma unroll
            for (int kk = 0; kk < BK; kk += 32) {
                bf16x8 af[4], bf[4];
                const int cl = (kk >> 3) + quad;   // logical 16B chunk
#pragma unroll
                for (int tm = 0; tm < 4; ++tm) {
                    int row = wm * 64 + tm * 16 + m16;
                    int p = cl ^ (row & 7);
                    af[tm] = *(const bf16x8*)&a_t[row * BK + p * 8];
                }
#pragma unroll
                for (int tn = 0; tn < 4; ++tn) {
                    int row = wn * 64 + tn * 16 + m16;
                    int p = cl ^ (row & 7);
                    bf[tn] = *(const bf16x8*)&b_t[row * BK + p * 8];
                }
#pragma unroll
                for (int tm = 0; tm < 4; ++tm)
#pragma unroll
                    for (int tn = 0; tn < 4; ++tn)
                        acc[tm][tn] = __builtin_amdgcn_mfma_f32_16x16x32_bf16(
                            af[tm], bf[tn], acc[tm][tn], 0, 0, 0);
            }
        }

        // ---- epilogue: d = sq_i + sq_j - 2 dot, clamp, e + e^2 + e^4 + e^8 + e^16 ----
        float lsum = 0.f;
#pragma unroll
        for (int tm = 0; tm < 4; ++tm) {
            const int i0 = wm * 64 + tm * 16 + quad * 4;
            float sqi[4] = {sqa[i0 + 0], sqa[i0 + 1], sqa[i0 + 2], sqa[i0 + 3]};
#pragma unroll
            for (int tn = 0; tn < 4; ++tn) {
                const int j = wn * 64 + tn * 16 + m16;
                const float sqj = sqb[j];
#pragma unroll
                for (int r = 0; r < 4; ++r) {
                    float d = fmaf(-2.f, acc[tm][tn][r], sqi[r] + sqj);
                    d = fmaxf(d, 0.f);
                    float e1 = __expf(d * ng0);
                    float e2 = e1 * e1, e4 = e2 * e2, e8 = e4 * e4, e16 = e8 * e8;
                    lsum += (e1 + e2) + (e4 + e8) + e16;
                }
            }
        }
        for (int off = 32; off; off >>= 1) lsum += __shfl_down(lsum, off);
        if (lane == 0) red[w] = lsum;
        __syncthreads();
        float wgt;
        if (bi == bj) wgt = 1.f;
        else wgt = ((bi < NBLK / 2) == (bj < NBLK / 2)) ? 2.f : -2.f;
        blocksum += (red[0] + red[1] + red[2] + red[3]) *
                    (wgt * (1.f / NUMK) * (1.f / 16777216.f));   // / (5 * 4096^2)
    }
    if (tid == 0) blockpart[bid] = blocksum;
    __threadfence();
    grid.sync();

    // ================= phase 4: final reduction =================
    if (bid == 0) {
        float s = 0.f;
        for (int i = tid; i < nb; i += 256) s += blockpart[i];
        for (int off = 32; off; off >>= 1) s += __shfl_down(s, off);
        if (lane == 0) red[w] = s;
        __syncthreads();
        if (tid == 0) out[0] = red[0] + red[1] + red[2] + red[3];
    }
}

extern "C" void kernel_launch(void* const* d_in, const int* in_sizes, int n_in,
                              void* d_out, int out_size, void* d_ws, size_t ws_size,
                              hipStream_t stream) {
    const float* s_feat = (const float*)d_in[0];
    const float* t_feat = (const float*)d_in[1];
    char* ws = (char*)d_ws;
    unsigned short* fb = (unsigned short*)(ws + WS_FB);
    float* sq        = (float*)(ws + WS_SQ);
    float* colpart   = (float*)(ws + WS_COLP);
    float* colpart2  = (float*)(ws + WS_COLP2);
    float* sqpart    = (float*)(ws + WS_SQP);
    float* blockpart = (float*)(ws + WS_BLKP);
    float* scal      = (float*)(ws + WS_SCAL);
    float* out       = (float*)d_out;

    int occ = 0;
    hipOccupancyMaxActiveBlocksPerMultiprocessor(&occ, mmd_all, 256, 0);
    if (occ < 1) occ = 1;
    long long nbl = (long long)occ * 256;
    if (nbl > GRID_MAX) nbl = GRID_MAX;

    void* args[] = {(void*)&s_feat, (void*)&t_feat, (void*)&fb, (void*)&sq,
                    (void*)&colpart, (void*)&colpart2, (void*)&sqpart,
                    (void*)&blockpart, (void*)&scal, (void*)&out};
    hipLaunchCooperativeKernel((void*)mmd_all, dim3((unsigned)nbl), dim3(256),
                               args, 0, stream);
}

// Round 6
// 146.087 us; speedup vs baseline: 3.2212x; 2.0530x over previous
//
#include <hip/hip_runtime.h>
#include <hip/hip_bf16.h>
#include <stdint.h>

// Problem constants
#define BATCH 4096
#define NT    8192          // 2*BATCH
#define FD    256           // feature dim
#define TILE  128           // block tile of the pair matrix
#define NBLK  64            // NT / TILE
#define NTRI  2080          // NBLK*(NBLK+1)/2 upper-triangle tiles
#define NUMK  5
#define NPART 128           // scattered partial cells for main reduction

typedef __attribute__((ext_vector_type(8))) short bf16x8;  // 8 bf16 = 4 VGPRs
typedef __attribute__((ext_vector_type(4))) float f32x4;

// ---- workspace layout (bytes) ----
static const size_t WS_FB    = 0;                          // bf16 feats [8192][256] = 4 MiB
static const size_t WS_SQ    = (size_t)NT * FD * 2;        // sq[8192] f32
// contiguous zero-init region: colsum[256] | sumsq | gamma | wsum[128]
static const size_t WS_ZERO  = WS_SQ + (size_t)NT * 4;
static const size_t WS_COL   = WS_ZERO;                    // colsum[256] f32
static const size_t WS_SUMSQ = WS_COL + 256 * 4;           // sumsq f32
static const size_t WS_GAMMA = WS_SUMSQ + 4;               // gamma f32
static const size_t WS_WSUM  = WS_GAMMA + 4;               // wsum[128] f32
static const size_t WS_ZEND  = WS_WSUM + NPART * 4;

__device__ __forceinline__ unsigned short f2bf_rne(float x) {
    unsigned u = __float_as_uint(x);
    unsigned r = (u + 0x7fffu + ((u >> 16) & 1u)) >> 16;
    return (unsigned short)r;
}

// ------- kernel 1: convert + row norms + colsum (128 blocks x 64 rows) -------
__global__ __launch_bounds__(256) void mmd_prep(
    const float* __restrict__ s_feat, const float* __restrict__ t_feat,
    unsigned short* __restrict__ fb, float* __restrict__ sq,
    float* __restrict__ colsum, float* __restrict__ sumsq) {
    __shared__ float cp[4][FD];
    __shared__ float red[4];
    const int w = threadIdx.x >> 6, lane = threadIdx.x & 63;
    float c0 = 0.f, c1 = 0.f, c2 = 0.f, c3 = 0.f, wtot = 0.f;
#pragma unroll
    for (int r = 0; r < 16; ++r) {
        int row = blockIdx.x * 64 + w * 16 + r;
        const float* src = (row < BATCH) ? (s_feat + (size_t)row * FD)
                                         : (t_feat + (size_t)(row - BATCH) * FD);
        float4 v = ((const float4*)src)[lane];
        unsigned int u01 = (unsigned)f2bf_rne(v.x) | ((unsigned)f2bf_rne(v.y) << 16);
        unsigned int u23 = (unsigned)f2bf_rne(v.z) | ((unsigned)f2bf_rne(v.w) << 16);
        ((uint2*)(fb + (size_t)row * FD))[lane] = make_uint2(u01, u23);
        float ss = v.x * v.x + v.y * v.y + v.z * v.z + v.w * v.w;
        for (int off = 32; off; off >>= 1) ss += __shfl_down(ss, off);
        if (lane == 0) { sq[row] = ss; wtot += ss; }
        c0 += v.x; c1 += v.y; c2 += v.z; c3 += v.w;
    }
    cp[w][4 * lane + 0] = c0;
    cp[w][4 * lane + 1] = c1;
    cp[w][4 * lane + 2] = c2;
    cp[w][4 * lane + 3] = c3;
    if (lane == 0) red[w] = wtot;
    __syncthreads();
    int t = threadIdx.x;
    atomicAdd(&colsum[t], cp[0][t] + cp[1][t] + cp[2][t] + cp[3][t]);
    if (t == 0) atomicAdd(sumsq, red[0] + red[1] + red[2] + red[3]);
}

// ------- kernel 2: bandwidth -> gamma (1 block) -------
__global__ void mmd_gamma(const float* __restrict__ colsum,
                          const float* __restrict__ sumsq,
                          float* __restrict__ gamma) {
    __shared__ float red[4];
    int t = threadIdx.x, lane = t & 63, w = t >> 6;
    float c = colsum[t];
    float v = c * c;
    for (int off = 32; off; off >>= 1) v += __shfl_down(v, off);
    if (lane == 0) red[w] = v;
    __syncthreads();
    if (t == 0) {
        float s2 = red[0] + red[1] + red[2] + red[3];
        // sum(distances) = 2*n*sum(sq) - 2*||colsum||^2 (diag clamp negligible)
        float sumd = 2.0f * (float)NT * sumsq[0] - 2.0f * s2;
        float n2n  = (float)((long long)NT * NT - NT);
        gamma[0]   = 0.25f * (n2n / sumd);   // bandwidth / 2^(NUM_KERNELS//2)
    }
}

// ------- kernel 3: GEMM + gaussian mixture, fully-global operands -------
// fb (4 MiB) is L2-resident; no LDS staging, ZERO barriers in the K-loop.
// Addressing: 8 constant base pointers, kk advances via load-offset immediates.
__global__ __launch_bounds__(256) void mmd_main(
    const unsigned short* __restrict__ fb,
    const float* __restrict__ sq,
    const float* __restrict__ gamma,
    float* __restrict__ wsum) {
    // decode upper-triangle linear index -> (bi, bj)
    int u = blockIdx.x, bi = 0;
    while (u >= NBLK - bi) { u -= NBLK - bi; ++bi; }
    const int bj = bi + u;

    __shared__ float red[4];
    const int tid  = threadIdx.x;
    const int w    = tid >> 6, lane = tid & 63;
    const int wm   = w & 1, wn = w >> 1;          // 2x2 waves over 128x128
    const int quad = lane >> 4, m16 = lane & 15;

    const int rowA0 = bi * TILE;
    const int rowB0 = bj * TILE;

    // fragment base pointers: lane covers row (base + x*16 + m16), chunk quad
    const unsigned short* ap[4];
    const unsigned short* bp[4];
#pragma unroll
    for (int x = 0; x < 4; ++x) {
        ap[x] = fb + (size_t)(rowA0 + wm * 64 + x * 16 + m16) * FD + quad * 8;
        bp[x] = fb + (size_t)(rowB0 + wn * 64 + x * 16 + m16) * FD + quad * 8;
    }

    const f32x4 fzero = {0.f, 0.f, 0.f, 0.f};
    f32x4 acc[4][4];
#pragma unroll
    for (int a = 0; a < 4; ++a)
#pragma unroll
        for (int b = 0; b < 4; ++b) acc[a][b] = fzero;

#pragma unroll
    for (int kk = 0; kk < 8; ++kk) {   // 8 x k32 steps; offsets are immediates
        bf16x8 af[4], bf[4];
#pragma unroll
        for (int x = 0; x < 4; ++x) {
            af[x] = *(const bf16x8*)(ap[x] + kk * 32);
            bf[x] = *(const bf16x8*)(bp[x] + kk * 32);
        }
#pragma unroll
        for (int tm = 0; tm < 4; ++tm)
#pragma unroll
            for (int tn = 0; tn < 4; ++tn)
                acc[tm][tn] = __builtin_amdgcn_mfma_f32_16x16x32_bf16(
                    af[tm], bf[tn], acc[tm][tn], 0, 0, 0);
    }

    // ---- epilogue: d = sq_i + sq_j - 2 dot, clamp, e + e^2 + e^4 + e^8 + e^16 ----
    const float ng0 = -gamma[0];
    float sqj[4];
#pragma unroll
    for (int tn = 0; tn < 4; ++tn) sqj[tn] = sq[rowB0 + wn * 64 + tn * 16 + m16];
    float lsum = 0.f;
#pragma unroll
    for (int tm = 0; tm < 4; ++tm) {
        const int i0 = rowA0 + wm * 64 + tm * 16 + quad * 4;
        float sqi[4] = {sq[i0 + 0], sq[i0 + 1], sq[i0 + 2], sq[i0 + 3]};
#pragma unroll
        for (int tn = 0; tn < 4; ++tn) {
#pragma unroll
            for (int r = 0; r < 4; ++r) {
                float d = fmaf(-2.f, acc[tm][tn][r], sqi[r] + sqj[tn]);
                d = fmaxf(d, 0.f);
                float e1 = __expf(d * ng0);
                float e2 = e1 * e1, e4 = e2 * e2, e8 = e4 * e4, e16 = e8 * e8;
                lsum += (e1 + e2) + (e4 + e8) + e16;
            }
        }
    }
    for (int off = 32; off; off >>= 1) lsum += __shfl_down(lsum, off);
    if (lane == 0) red[w] = lsum;
    __syncthreads();
    if (tid == 0) {
        float wgt;
        if (bi == bj) wgt = 1.f;                                  // diagonal tile
        else wgt = ((bi < NBLK / 2) == (bj < NBLK / 2)) ? 2.f : -2.f;
        float scale = wgt * (1.f / NUMK) * (1.f / 16777216.f);    // / (5 * 4096^2)
        atomicAdd(&wsum[blockIdx.x & (NPART - 1)],
                  (red[0] + red[1] + red[2] + red[3]) * scale);
    }
}

// ------- kernel 4: final reduction (1 wave) -------
__global__ void mmd_final(const float* __restrict__ wsum, float* __restrict__ out) {
    int lane = threadIdx.x;
    float s = wsum[lane] + wsum[lane + 64];
    for (int off = 32; off; off >>= 1) s += __shfl_down(s, off);
    if (lane == 0) out[0] = s;
}

extern "C" void kernel_launch(void* const* d_in, const int* in_sizes, int n_in,
                              void* d_out, int out_size, void* d_ws, size_t ws_size,
                              hipStream_t stream) {
    const float* s_feat = (const float*)d_in[0];
    const float* t_feat = (const float*)d_in[1];
    char* ws = (char*)d_ws;
    unsigned short* fb = (unsigned short*)(ws + WS_FB);
    float* sq     = (float*)(ws + WS_SQ);
    float* colsum = (float*)(ws + WS_COL);
    float* sumsq  = (float*)(ws + WS_SUMSQ);
    float* gamma  = (float*)(ws + WS_GAMMA);
    float* wsum   = (float*)(ws + WS_WSUM);
    float* out    = (float*)d_out;

    hipMemsetAsync(ws + WS_ZERO, 0, WS_ZEND - WS_ZERO, stream);  // colsum|sumsq|gamma|wsum

    mmd_prep<<<NT / 64, 256, 0, stream>>>(s_feat, t_feat, fb, sq, colsum, sumsq);
    mmd_gamma<<<1, 256, 0, stream>>>(colsum, sumsq, gamma);
    mmd_main<<<NTRI, 256, 0, stream>>>(fb, sq, gamma, wsum);
    mmd_final<<<1, 64, 0, stream>>>(wsum, out);
}